// Round 5
// baseline (501.368 us; speedup 1.0000x reference)
//
#include <hip/hip_runtime.h>

#define NN   20000
#define NE   320000
#define EAD  8
#define DIN  16
#define DOUT 16
#define HH   256      // DIN*DOUT
#define SLOPE 0.01f
#define EPB  64       // edges per block

typedef __attribute__((ext_vector_type(8))) short bf16x8;   // 8 bf16 = 4 VGPRs
typedef __attribute__((ext_vector_type(4))) float f32x4;    // MFMA C/D

__device__ __forceinline__ float leakyf(float v) { return v >= 0.f ? v : SLOPE * v; }

// fp32 -> bf16 round-to-nearest-even
__device__ __forceinline__ unsigned short f2bf(float f) {
    unsigned int u = __builtin_bit_cast(unsigned int, f);
    u += 0x7FFFu + ((u >> 16) & 1u);
    return (unsigned short)(u >> 16);
}
__device__ __forceinline__ float bf2f(unsigned short h) {
    unsigned int u = ((unsigned int)h) << 16;
    return __builtin_bit_cast(float, u);
}

// prep: w2 -> w2T[c][j] bf16 (both layers), w1 -> w1T[j][k] bf16 (both layers)
__global__ void prep_kernel(const float* __restrict__ w2_0, const float* __restrict__ w2_1,
                            const float* __restrict__ w1_0, const float* __restrict__ w1_1,
                            unsigned short* __restrict__ w2T0, unsigned short* __restrict__ w2T1,
                            unsigned short* __restrict__ w1T0, unsigned short* __restrict__ w1T1)
{
    int idx = blockIdx.x * 256 + threadIdx.x;
    if (idx < HH * HH) {
        int c = idx >> 8, j = idx & 255;
        w2T0[idx] = f2bf(w2_0[j * HH + c]);
        w2T1[idx] = f2bf(w2_1[j * HH + c]);
    }
    if (idx < HH * EAD) {
        int j = idx >> 3, k = idx & 7;
        w1T0[idx] = f2bf(w1_0[k * HH + j]);
        w1T1[idx] = f2bf(w1_1[k * HH + j]);
    }
}

// degree histogram (int atomics, 1 per edge)
__global__ void deg_kernel(const int* __restrict__ edst, int* __restrict__ deg)
{
    int e = blockIdx.x * 256 + threadIdx.x;
    if (e < NE) atomicAdd(&deg[edst[e]], 1);
}

// exclusive scan of deg[NN] -> start[NN+1], and two cursor copies (one per layer)
__global__ void scan_kernel(const int* __restrict__ deg,
                            int* __restrict__ start,
                            int* __restrict__ curA,
                            int* __restrict__ curB)
{
    __shared__ int warp_sums[16];
    __shared__ int base_s;
    const int tid = threadIdx.x;
    const int lane = tid & 63, wv = tid >> 6;
    if (tid == 0) base_s = 0;
    __syncthreads();
    const int NCHUNK = (NN + 1023) / 1024;
    for (int c = 0; c < NCHUNK; ++c) {
        int i = c * 1024 + tid;
        int v = (i < NN) ? deg[i] : 0;
        int s = v;
        #pragma unroll
        for (int off = 1; off < 64; off <<= 1) {
            int u = __shfl_up(s, off);
            if (lane >= off) s += u;
        }
        if (lane == 63) warp_sums[wv] = s;
        __syncthreads();
        if (wv == 0) {
            int ws = (lane < 16) ? warp_sums[lane] : 0;
            int t = ws;
            #pragma unroll
            for (int off = 1; off < 16; off <<= 1) {
                int u = __shfl_up(t, off);
                if (lane >= off) t += u;
            }
            if (lane < 16) warp_sums[lane] = t - ws;   // exclusive wave prefix
        }
        __syncthreads();
        int excl = base_s + warp_sums[wv] + (s - v);
        if (i < NN) { start[i] = excl; curA[i] = excl; curB[i] = excl; }
        __syncthreads();
        if (wv == 15 && lane == 63) base_s += warp_sums[15] + s;  // chunk total
        __syncthreads();
    }
    if (tid == 0) start[NN] = NE;
}

// Fused NNConv message pass, MFMA version, bucketed msg store (no fp32 atomics).
// h = leaky(ea@w1+b1) via 16x16x32 MFMA (K=8 padded); W = h@w2 + b2 via MFMA
// (b2 folded into acc init); msg = x[src]@W reduced in LDS; msg row written
// bf16 at CSR-bucketed position (1 int atomic per edge).
__global__ __launch_bounds__(256, 2)
void edge_kernel(const float* __restrict__ x,      // [NN,16]
                 const int*   __restrict__ esrc,   // [NE]
                 const int*   __restrict__ edst,   // [NE]
                 const float* __restrict__ ea,     // [NE,8]
                 const unsigned short* __restrict__ w1T, // [256 j][8 k] bf16
                 const float* __restrict__ b1,     // [256]
                 const unsigned short* __restrict__ w2T, // [256 c][256 j] bf16
                 const float* __restrict__ b2,     // [256]
                 int* __restrict__ cursor,         // [NN] slot cursors
                 unsigned short* __restrict__ msgbuf) // [NE,16] bf16
{
    __shared__ __align__(16) unsigned short h_us[EPB * HH]; // 32 KB, XOR-swizzled rows
    __shared__ float xs[EPB][DIN];                          // 4 KB
    __shared__ float msg_s[EPB][DOUT];                      // 4 KB
    __shared__ int   spos[EPB];

    const int tid = threadIdx.x;
    const int e0  = blockIdx.x * EPB;
    const int w   = tid >> 6;   // wave 0..3 -> col slab 64w..64w+63
    const int ln  = tid & 63;
    const int lo  = ln & 15;
    const int g4  = ln >> 4;    // 0..3

    // claim output slots early (latency hidden under phases 1-2)
    if (tid < EPB) spos[tid] = atomicAdd(&cursor[edst[e0 + tid]], 1);

    // zero msg accumulator (1024 floats)
    #pragma unroll
    for (int z = 0; z < 4; ++z) ((float*)msg_s)[z * 256 + tid] = 0.f;

    // gather x[src]: 64 edges x 16 f32 (4 lanes per edge, float4 each)
    {
        int t = tid >> 2, p = tid & 3;
        int s = esrc[e0 + t];
        *(float4*)&xs[t][p * 4] = *(const float4*)(x + (size_t)s * DIN + p * 4);
    }

    // ---- phase 1: h = leaky(ea @ w1 + b1) via MFMA (K padded 8->32) ----
    bf16x8 zero8;
    #pragma unroll
    for (int k = 0; k < 8; ++k) zero8[k] = 0;

    bf16x8 aE[4], bW[4];
    #pragma unroll
    for (int mt = 0; mt < 4; ++mt) aE[mt] = zero8;
    #pragma unroll
    for (int nt = 0; nt < 4; ++nt) bW[nt] = zero8;

    if (ln < 16) {  // lanes 0-15 carry k=0..7 (real); lanes 16-63 carry zeros
        #pragma unroll
        for (int mt = 0; mt < 4; ++mt) {
            const float* p = ea + (size_t)(e0 + 16 * mt + lo) * EAD;
            bf16x8 v;
            #pragma unroll
            for (int k = 0; k < 8; ++k) v[k] = (short)f2bf(p[k]);
            aE[mt] = v;
        }
        #pragma unroll
        for (int nt = 0; nt < 4; ++nt) {
            int j = 64 * w + 16 * nt + lo;
            bW[nt] = *(const bf16x8*)(w1T + j * EAD);
        }
    }

    f32x4 hacc[4][4];
    #pragma unroll
    for (int nt = 0; nt < 4; ++nt) {
        float bv = b1[64 * w + 16 * nt + lo];
        f32x4 bi; bi[0] = bv; bi[1] = bv; bi[2] = bv; bi[3] = bv;
        #pragma unroll
        for (int mt = 0; mt < 4; ++mt) hacc[mt][nt] = bi;
    }
    #pragma unroll
    for (int mt = 0; mt < 4; ++mt)
        #pragma unroll
        for (int nt = 0; nt < 4; ++nt)
            hacc[mt][nt] = __builtin_amdgcn_mfma_f32_16x16x32_bf16(aE[mt], bW[nt], hacc[mt][nt], 0, 0, 0);

    // leaky + bf16 pack + swizzled LDS store. D layout: col=lane&15, row=(lane>>4)*4+r
    #pragma unroll
    for (int mt = 0; mt < 4; ++mt)
        #pragma unroll
        for (int nt = 0; nt < 4; ++nt)
            #pragma unroll
            for (int r = 0; r < 4; ++r) {
                int t = 16 * mt + 4 * g4 + r;
                int j = 64 * w + 16 * nt + lo;
                h_us[(t * HH + j) ^ ((t & 7) << 3)] = f2bf(leakyf(hacc[mt][nt][r]));
            }
    __syncthreads();

    // ---- phase 2: W = h @ w2 + b2  (M=64 edges, N=256 cols, K=256) ----
    f32x4 acc[4][4];
    {
        #pragma unroll
        for (int nt = 0; nt < 4; ++nt) {
            float bv = b2[64 * w + 16 * nt + lo];   // b2[c], c=(i,o) col of W
            f32x4 bi; bi[0] = bv; bi[1] = bv; bi[2] = bv; bi[3] = bv;
            #pragma unroll
            for (int mt = 0; mt < 4; ++mt) acc[mt][nt] = bi;
        }
    }
    // B-frag: lane holds w2T[c=64w+16nt+lo][j=32ks+8g4 .. +8]; register double-buffer
    const unsigned short* bbase = w2T + (size_t)(64 * w + lo) * HH + 8 * g4;
    bf16x8 bcur[4], bnxt[4];
    #pragma unroll
    for (int nt = 0; nt < 4; ++nt) bcur[nt] = *(const bf16x8*)(bbase + nt * 16 * HH);
    #pragma unroll
    for (int nt = 0; nt < 4; ++nt) bnxt[nt] = bcur[nt];

    #pragma unroll
    for (int ks = 0; ks < 8; ++ks) {
        if (ks < 7) {
            #pragma unroll
            for (int nt = 0; nt < 4; ++nt)
                bnxt[nt] = *(const bf16x8*)(bbase + nt * 16 * HH + 32 * (ks + 1));
        }
        bf16x8 af[4];   // A-frag: lane holds h[t=16mt+lo][j=32ks+8g4 .. +8]
        #pragma unroll
        for (int mt = 0; mt < 4; ++mt) {
            int t = 16 * mt + lo;
            af[mt] = *(const bf16x8*)(h_us + ((t * HH + 32 * ks + 8 * g4) ^ ((t & 7) << 3)));
        }
        #pragma unroll
        for (int mt = 0; mt < 4; ++mt)
            #pragma unroll
            for (int nt = 0; nt < 4; ++nt)
                acc[mt][nt] = __builtin_amdgcn_mfma_f32_16x16x32_bf16(af[mt], bcur[nt], acc[mt][nt], 0, 0, 0);
        #pragma unroll
        for (int nt = 0; nt < 4; ++nt) bcur[nt] = bnxt[nt];
    }

    // ---- epilogue: msg[t][o] += sum_i xs[t][i] * W[t][16i+o] ----
    // lane's col c = 64w+16nt+lo  ->  i = 4w+nt, o = lo  (b2 already inside acc)
    #pragma unroll
    for (int mt = 0; mt < 4; ++mt)
        #pragma unroll
        for (int r = 0; r < 4; ++r) {
            int t = 16 * mt + 4 * g4 + r;
            float ps = 0.f;
            #pragma unroll
            for (int nt = 0; nt < 4; ++nt)
                ps += xs[t][4 * w + nt] * acc[mt][nt][r];
            atomicAdd(&msg_s[t][lo], ps);
        }
    __syncthreads();

    // ---- tail: write msg row (bf16) at bucketed slot; coalesced 8B/thread ----
    {
        int t = tid >> 2, p = tid & 3;
        float4 m = *(const float4*)&msg_s[t][p * 4];
        unsigned int w0 = (unsigned int)f2bf(m.x) | ((unsigned int)f2bf(m.y) << 16);
        unsigned int w1v = (unsigned int)f2bf(m.z) | ((unsigned int)f2bf(m.w) << 16);
        uint2 pk; pk.x = w0; pk.y = w1v;
        *(uint2*)&msgbuf[(size_t)spos[t] * DOUT + p * 4] = pk;
    }
}

// per node: mean over its contiguous msg bucket + root transform + bias (+leaky)
__global__ void gather_kernel(const unsigned short* __restrict__ msgbuf, // [NE,16] bf16
                              const int* __restrict__ start,             // [NN+1]
                              const float* __restrict__ xin,             // [NN,16]
                              const float* __restrict__ root,            // [16,16]
                              const float* __restrict__ bias,            // [16]
                              float* __restrict__ out,                   // [NN,16]
                              int do_leaky)
{
    __shared__ float xs_l[16][16];
    __shared__ float root_s[256];
    const int tid = threadIdx.x;
    const int node0 = blockIdx.x * 16;
    root_s[tid] = root[tid];
    xs_l[tid >> 4][tid & 15] = xin[node0 * DIN + tid];
    __syncthreads();

    const int nl = tid >> 4, o = tid & 15;
    const int n = node0 + nl;
    const int s = start[n], e = start[n + 1];
    float v = 0.f, v2 = 0.f;
    int p = s;
    for (; p + 1 < e; p += 2) {
        v  += bf2f(msgbuf[(size_t)p * DOUT + o]);
        v2 += bf2f(msgbuf[(size_t)(p + 1) * DOUT + o]);
    }
    if (p < e) v += bf2f(msgbuf[(size_t)p * DOUT + o]);
    v += v2;
    float d = (float)(e - s);
    d = d > 1.f ? d : 1.f;
    v /= d;
    float r = 0.f;
    #pragma unroll
    for (int i = 0; i < DIN; ++i)
        r += xs_l[nl][i] * root_s[i * DOUT + o];
    v += r + bias[o];
    out[(size_t)n * DOUT + o] = do_leaky ? leakyf(v) : v;
}

extern "C" void kernel_launch(void* const* d_in, const int* in_sizes, int n_in,
                              void* d_out, int out_size, void* d_ws, size_t ws_size,
                              hipStream_t stream)
{
    const float* x      = (const float*)d_in[0];
    const int*   ei     = (const int*)  d_in[1];
    const float* ea     = (const float*)d_in[2];
    const float* w1_0   = (const float*)d_in[3];
    const float* b1_0   = (const float*)d_in[4];
    const float* w2_0   = (const float*)d_in[5];
    const float* b2_0   = (const float*)d_in[6];
    const float* root_0 = (const float*)d_in[7];
    const float* bias_0 = (const float*)d_in[8];
    const float* w1_1   = (const float*)d_in[9];
    const float* b1_1   = (const float*)d_in[10];
    const float* w2_1   = (const float*)d_in[11];
    const float* b2_1   = (const float*)d_in[12];
    const float* root_1 = (const float*)d_in[13];
    const float* bias_1 = (const float*)d_in[14];

    const int* esrc = ei;
    const int* edst = ei + NE;

    // ws layout:
    //  w2T0|w2T1 (2*65536 us) | w1T0|w1T1 (2*2048 us) | msg [NE*16] us |
    //  deg [NN] | start [NN+1] | curA [NN] | curB [NN] (ints) | x1 [NN*16] f32
    unsigned short* w2T0 = (unsigned short*)d_ws;
    unsigned short* w2T1 = w2T0 + HH * HH;
    unsigned short* w1T0 = w2T1 + HH * HH;
    unsigned short* w1T1 = w1T0 + HH * EAD;
    unsigned short* msg  = w1T1 + HH * EAD;
    int* deg   = (int*)(msg + (size_t)NE * DOUT);
    int* start = deg + NN;
    int* curA  = start + NN + 1;
    int* curB  = curA + NN;
    float* x1  = (float*)(curB + NN);

    const size_t ws_need = (size_t)((char*)(x1 + (size_t)NN * DIN) - (char*)d_ws);
    if (ws_size < ws_need) return;  // fail clean (absmax), not a GPU fault

    hipMemsetAsync(deg, 0, (size_t)NN * sizeof(int), stream);
    prep_kernel<<<HH * HH / 256, 256, 0, stream>>>(w2_0, w2_1, w1_0, w1_1,
                                                   w2T0, w2T1, w1T0, w1T1);
    deg_kernel<<<(NE + 255) / 256, 256, 0, stream>>>(edst, deg);
    scan_kernel<<<1, 1024, 0, stream>>>(deg, start, curA, curB);

    edge_kernel<<<NE / EPB, 256, 0, stream>>>(x, esrc, edst, ea,
                                              w1T0, b1_0, w2T0, b2_0, curA, msg);
    gather_kernel<<<NN / 16, 256, 0, stream>>>(msg, start, x, root_0, bias_0, x1, 1);

    edge_kernel<<<NE / EPB, 256, 0, stream>>>(x1, esrc, edst, ea,
                                              w1T1, b1_1, w2T1, b2_1, curB, msg);
    gather_kernel<<<NN / 16, 256, 0, stream>>>(msg, start, x1, root_1, bias_1,
                                               (float*)d_out, 0);
}

// Round 6
// 335.031 us; speedup vs baseline: 1.4965x; 1.4965x over previous
//
#include <hip/hip_runtime.h>

#define NN   20000
#define NE   320000
#define EAD  8
#define DIN  16
#define DOUT 16
#define HH   256      // DIN*DOUT
#define SLOPE 0.01f
#define EPB  64       // edges per block
#define MPS  17       // msg_p padded stride (floats)

typedef __attribute__((ext_vector_type(8))) short bf16x8;   // 8 bf16 = 4 VGPRs
typedef __attribute__((ext_vector_type(4))) float f32x4;    // MFMA C/D

__device__ __forceinline__ float leakyf(float v) { return v >= 0.f ? v : SLOPE * v; }

// fp32 -> bf16 round-to-nearest-even
__device__ __forceinline__ unsigned short f2bf(float f) {
    unsigned int u = __builtin_bit_cast(unsigned int, f);
    u += 0x7FFFu + ((u >> 16) & 1u);
    return (unsigned short)(u >> 16);
}

// prep: w2 -> w2T[c][j] bf16 (both layers), w1 -> w1T[j][k] bf16 (both layers)
__global__ void prep_kernel(const float* __restrict__ w2_0, const float* __restrict__ w2_1,
                            const float* __restrict__ w1_0, const float* __restrict__ w1_1,
                            unsigned short* __restrict__ w2T0, unsigned short* __restrict__ w2T1,
                            unsigned short* __restrict__ w1T0, unsigned short* __restrict__ w1T1)
{
    int idx = blockIdx.x * 256 + threadIdx.x;
    if (idx < HH * HH) {
        int c = idx >> 8, j = idx & 255;
        w2T0[idx] = f2bf(w2_0[j * HH + c]);
        w2T1[idx] = f2bf(w2_1[j * HH + c]);
    }
    if (idx < HH * EAD) {
        int j = idx >> 3, k = idx & 7;
        w1T0[idx] = f2bf(w1_0[k * HH + j]);
        w1T1[idx] = f2bf(w1_1[k * HH + j]);
    }
}

// Fused NNConv message pass (MFMA). Phase-1 computes h TRANSPOSED
// (D rows = j) so the LDS store vectorizes to b64; phase-2 unchanged.
template<int COUNT>
__global__ __launch_bounds__(256, 3)
void edge_kernel(const float* __restrict__ x,      // [NN,16]
                 const int*   __restrict__ esrc,   // [NE]
                 const int*   __restrict__ edst,   // [NE]
                 const float* __restrict__ ea,     // [NE,8]
                 const unsigned short* __restrict__ w1T, // [256 j][8 k] bf16
                 const float* __restrict__ b1,     // [256]
                 const unsigned short* __restrict__ w2T, // [256 c][256 j] bf16
                 const float* __restrict__ b2,     // [256]
                 float* __restrict__ agg,          // [NN,16]
                 float* __restrict__ cnt)          // [NN]
{
    __shared__ __align__(16) unsigned short h_us[EPB * HH];  // 32 KB, ^((t&7)<<3) swizzle
    __shared__ float msg_p[4][EPB][MPS];                     // 17 KB per-wave partials
    __shared__ int   ssrc[EPB];
    __shared__ int   sdst[EPB];
    // total ~50 KB -> 3 blocks/CU

    const int tid = threadIdx.x;
    const int e0  = blockIdx.x * EPB;
    const int w   = tid >> 6;   // wave 0..3
    const int ln  = tid & 63;
    const int lo  = ln & 15;
    const int g4  = ln >> 4;    // 0..3

    if (tid < EPB) {
        ssrc[tid] = esrc[e0 + tid];
        sdst[tid] = edst[e0 + tid];
    }

    // hoist phase-2 ks=0 B-frags (w2T, L2-resident) above phase-1
    const unsigned short* bbase = w2T + (size_t)(64 * w + lo) * HH + 8 * g4;
    bf16x8 bcur[4], bnxt[4];
    #pragma unroll
    for (int nt = 0; nt < 4; ++nt) bcur[nt] = *(const bf16x8*)(bbase + nt * 16 * HH);

    // ---- phase 1 (transposed): hT[j][t] = leaky(sum_k w1T[j][k] ea[t][k] + b1[j]) ----
    bf16x8 zero8;
    #pragma unroll
    for (int k = 0; k < 8; ++k) zero8[k] = 0;

    bf16x8 aW[4], bE[4];   // A = w1 rows (j), B = ea rows (t); K padded 8->32
    #pragma unroll
    for (int q = 0; q < 4; ++q) { aW[q] = zero8; bE[q] = zero8; }

    if (ln < 16) {  // g4==0 lanes carry k=0..7; others zero
        #pragma unroll
        for (int jj = 0; jj < 4; ++jj)
            aW[jj] = *(const bf16x8*)(w1T + ((4 * w + jj) * 16 + lo) * EAD);
        #pragma unroll
        for (int tb = 0; tb < 4; ++tb) {
            const float* p = ea + (size_t)(e0 + 16 * tb + lo) * EAD;
            bf16x8 v;
            #pragma unroll
            for (int k = 0; k < 8; ++k) v[k] = (short)f2bf(p[k]);
            bE[tb] = v;
        }
    }

    f32x4 hacc[4][4];   // [jj][tb]
    #pragma unroll
    for (int jj = 0; jj < 4; ++jj) {
        float4 bv = *(const float4*)(b1 + (4 * w + jj) * 16 + 4 * g4);  // b1[j0..j0+3]
        f32x4 bi; bi[0] = bv.x; bi[1] = bv.y; bi[2] = bv.z; bi[3] = bv.w;
        #pragma unroll
        for (int tb = 0; tb < 4; ++tb) hacc[jj][tb] = bi;
    }
    #pragma unroll
    for (int jj = 0; jj < 4; ++jj)
        #pragma unroll
        for (int tb = 0; tb < 4; ++tb)
            hacc[jj][tb] = __builtin_amdgcn_mfma_f32_16x16x32_bf16(aW[jj], bE[tb], hacc[jj][tb], 0, 0, 0);

    // leaky + pack 4 consecutive j (D rows) -> one b64 store
    // element h[t][j] lives at u16 idx (t*256+j)^((t&7)<<3)
    #pragma unroll
    for (int jj = 0; jj < 4; ++jj) {
        const int j0 = 64 * w + 16 * jj + 4 * g4;
        #pragma unroll
        for (int tb = 0; tb < 4; ++tb) {
            const int t = 16 * tb + lo;
            unsigned int u0 = (unsigned int)f2bf(leakyf(hacc[jj][tb][0]))
                            | ((unsigned int)f2bf(leakyf(hacc[jj][tb][1])) << 16);
            unsigned int u1 = (unsigned int)f2bf(leakyf(hacc[jj][tb][2]))
                            | ((unsigned int)f2bf(leakyf(hacc[jj][tb][3])) << 16);
            uint2 pk; pk.x = u0; pk.y = u1;
            *(uint2*)&h_us[(t * HH + j0) ^ ((t & 7) << 3)] = pk;
        }
    }
    __syncthreads();

    // ---- phase 2: W = h @ w2 + b2  (M=64 edges, N=256 cols, K=256) ----
    f32x4 acc[4][4];
    #pragma unroll
    for (int nt = 0; nt < 4; ++nt) {
        float bv = b2[64 * w + 16 * nt + lo];
        f32x4 bi; bi[0] = bv; bi[1] = bv; bi[2] = bv; bi[3] = bv;
        #pragma unroll
        for (int mt = 0; mt < 4; ++mt) acc[mt][nt] = bi;
    }
    #pragma unroll
    for (int ks = 0; ks < 8; ++ks) {
        if (ks < 7) {
            #pragma unroll
            for (int nt = 0; nt < 4; ++nt)
                bnxt[nt] = *(const bf16x8*)(bbase + nt * 16 * HH + 32 * (ks + 1));
        }
        bf16x8 af[4];   // lane: h[t=16mt+lo][j=32ks+8g4 .. +8]
        #pragma unroll
        for (int mt = 0; mt < 4; ++mt) {
            int t = 16 * mt + lo;
            af[mt] = *(const bf16x8*)(h_us + ((t * HH + 32 * ks + 8 * g4) ^ ((t & 7) << 3)));
        }
        #pragma unroll
        for (int mt = 0; mt < 4; ++mt)
            #pragma unroll
            for (int nt = 0; nt < 4; ++nt)
                acc[mt][nt] = __builtin_amdgcn_mfma_f32_16x16x32_bf16(af[mt], bcur[nt], acc[mt][nt], 0, 0, 0);
        #pragma unroll
        for (int nt = 0; nt < 4; ++nt) bcur[nt] = bnxt[nt];
    }

    // ---- epilogue: per-wave partial msg (i-slice 4w..4w+3), x read from global ----
    // lane's col c = 64w+16nt+lo -> i = 4w+nt, o = lo; D row -> t = 16mt+4g4+r
    #pragma unroll
    for (int mt = 0; mt < 4; ++mt)
        #pragma unroll
        for (int r = 0; r < 4; ++r) {
            const int t = 16 * mt + 4 * g4 + r;
            float4 xv = *(const float4*)(x + (size_t)ssrc[t] * DIN + 4 * w);  // 16-lane broadcast
            float ps = xv.x * acc[mt][0][r] + xv.y * acc[mt][1][r]
                     + xv.z * acc[mt][2][r] + xv.w * acc[mt][3][r];
            msg_p[w][t][lo] = ps;
        }
    __syncthreads();

    // ---- tail: sum 4 wave-partials, scatter with global fp32 atomics ----
    {
        const int t = tid >> 2, p = tid & 3;
        const int d = sdst[t];
        #pragma unroll
        for (int oo = 0; oo < 4; ++oo) {
            const int o = 4 * p + oo;
            float m = msg_p[0][t][o] + msg_p[1][t][o] + msg_p[2][t][o] + msg_p[3][t][o];
            atomicAdd(&agg[(size_t)d * DOUT + o], m);
        }
        if (COUNT && p == 0) atomicAdd(&cnt[d], 1.0f);
    }
}

// out[n][o] = agg[n][o]/max(cnt,1) + x[n]@root[:,o] + bias[o]  (opt leaky)
__global__ void finalize_kernel(const float* __restrict__ agg,
                                const float* __restrict__ cnt,
                                const float* __restrict__ xin,
                                const float* __restrict__ root, // [16,16]
                                const float* __restrict__ bias, // [16]
                                float* __restrict__ out,
                                int do_leaky)
{
    int idx = blockIdx.x * blockDim.x + threadIdx.x;
    if (idx >= NN * DOUT) return;
    int n = idx >> 4, o = idx & 15;
    float c = cnt[n];
    c = c > 1.f ? c : 1.f;
    float v = agg[idx] / c;
    #pragma unroll
    for (int i = 0; i < DIN; ++i)
        v += xin[n * DIN + i] * root[i * DOUT + o];
    v += bias[o];
    out[idx] = do_leaky ? leakyf(v) : v;
}

extern "C" void kernel_launch(void* const* d_in, const int* in_sizes, int n_in,
                              void* d_out, int out_size, void* d_ws, size_t ws_size,
                              hipStream_t stream)
{
    const float* x      = (const float*)d_in[0];
    const int*   ei     = (const int*)  d_in[1];
    const float* ea     = (const float*)d_in[2];
    const float* w1_0   = (const float*)d_in[3];
    const float* b1_0   = (const float*)d_in[4];
    const float* w2_0   = (const float*)d_in[5];
    const float* b2_0   = (const float*)d_in[6];
    const float* root_0 = (const float*)d_in[7];
    const float* bias_0 = (const float*)d_in[8];
    const float* w1_1   = (const float*)d_in[9];
    const float* b1_1   = (const float*)d_in[10];
    const float* w2_1   = (const float*)d_in[11];
    const float* b2_1   = (const float*)d_in[12];
    const float* root_1 = (const float*)d_in[13];
    const float* bias_1 = (const float*)d_in[14];

    const int* esrc = ei;
    const int* edst = ei + NE;

    // ws: w2T0|w2T1 (bf16) | w1T0|w1T1 (bf16) | agg | cnt | x1 (f32)
    unsigned short* w2T0 = (unsigned short*)d_ws;
    unsigned short* w2T1 = w2T0 + HH * HH;
    unsigned short* w1T0 = w2T1 + HH * HH;
    unsigned short* w1T1 = w1T0 + HH * EAD;
    float* agg = (float*)(w1T1 + HH * EAD);
    float* cnt = agg + (size_t)NN * DOUT;
    float* x1  = cnt + NN;
    const size_t ws_need = (size_t)((char*)(x1 + (size_t)NN * DIN) - (char*)d_ws);
    if (ws_size < ws_need) return;  // fail clean (absmax), not a GPU fault

    hipMemsetAsync(agg, 0, ((size_t)NN * DOUT + NN) * sizeof(float), stream);
    prep_kernel<<<HH * HH / 256, 256, 0, stream>>>(w2_0, w2_1, w1_0, w1_1,
                                                   w2T0, w2T1, w1T0, w1T1);

    edge_kernel<1><<<NE / EPB, 256, 0, stream>>>(x, esrc, edst, ea,
                                                 w1T0, b1_0, w2T0, b2_0, agg, cnt);
    finalize_kernel<<<(NN * DOUT + 255) / 256, 256, 0, stream>>>(agg, cnt, x,
                                                 root_0, bias_0, x1, 1);
    hipMemsetAsync(agg, 0, (size_t)NN * DOUT * sizeof(float), stream);

    edge_kernel<0><<<NE / EPB, 256, 0, stream>>>(x1, esrc, edst, ea,
                                                 w1T1, b1_1, w2T1, b2_1, agg, cnt);
    finalize_kernel<<<(NN * DOUT + 255) / 256, 256, 0, stream>>>(agg, cnt, x1,
                                                 root_1, bias_1, (float*)d_out, 0);
}

// Round 9
// 334.407 us; speedup vs baseline: 1.4993x; 1.0019x over previous
//
#include <hip/hip_runtime.h>

#define NN   20000
#define NE   320000
#define EAD  8
#define DIN  16
#define DOUT 16
#define HH   256      // DIN*DOUT
#define SLOPE 0.01f
#define EPB  64       // edges per block
#define MPS  17       // msg partial padded stride (floats)

typedef __attribute__((ext_vector_type(8))) short bf16x8;   // 8 bf16 = 4 VGPRs
typedef __attribute__((ext_vector_type(4))) float f32x4;    // MFMA C/D

__device__ __forceinline__ float leakyf(float v) { return v >= 0.f ? v : SLOPE * v; }

// fp32 -> bf16 round-to-nearest-even
__device__ __forceinline__ unsigned short f2bf(float f) {
    unsigned int u = __builtin_bit_cast(unsigned int, f);
    u += 0x7FFFu + ((u >> 16) & 1u);
    return (unsigned short)(u >> 16);
}

// swizzle: XOR u16-index bits 4-5 with t&3 — disjoint from the 8*g4 fragment
// offset (bits 3-4 of the b128 group), so phase-2 reads AND phase-1 b64 stores
// land 2 dwords/bank/cycle (free aliasing level).
#define HSWZ(t, idx) ((idx) ^ (((t) & 3) << 4))

// prep: w2 -> w2T[c][j] bf16 (both layers), w1 -> w1T[j][k] bf16 (both layers)
__global__ void prep_kernel(const float* __restrict__ w2_0, const float* __restrict__ w2_1,
                            const float* __restrict__ w1_0, const float* __restrict__ w1_1,
                            unsigned short* __restrict__ w2T0, unsigned short* __restrict__ w2T1,
                            unsigned short* __restrict__ w1T0, unsigned short* __restrict__ w1T1)
{
    int idx = blockIdx.x * 256 + threadIdx.x;
    if (idx < HH * HH) {
        int c = idx >> 8, j = idx & 255;
        w2T0[idx] = f2bf(w2_0[j * HH + c]);
        w2T1[idx] = f2bf(w2_1[j * HH + c]);
    }
    if (idx < HH * EAD) {
        int j = idx >> 3, k = idx & 7;
        w1T0[idx] = f2bf(w1_0[k * HH + j]);
        w1T1[idx] = f2bf(w1_1[k * HH + j]);
    }
}

// Fused NNConv message pass (MFMA), 3-barrier, h_us reused for msg partials.
template<int COUNT>
__global__ __launch_bounds__(256, 4)
void edge_kernel(const float* __restrict__ x,      // [NN,16]
                 const int*   __restrict__ esrc,   // [NE]
                 const int*   __restrict__ edst,   // [NE]
                 const float* __restrict__ ea,     // [NE,8]
                 const unsigned short* __restrict__ w1T, // [256 j][8 k] bf16
                 const float* __restrict__ b1,     // [256]
                 const unsigned short* __restrict__ w2T, // [256 c][256 j] bf16
                 const float* __restrict__ b2,     // [256]
                 float* __restrict__ agg,          // [NN,16]
                 float* __restrict__ cnt)          // [NN]
{
    __shared__ __align__(16) unsigned short h_us[EPB * HH];  // 32 KB; reused as msg partials
    __shared__ int ssrc[EPB];
    __shared__ int sdst[EPB];
    // total ~33.3 KB -> 4 blocks/CU

    const int tid = threadIdx.x;
    const int e0  = blockIdx.x * EPB;
    const int w   = tid >> 6;   // wave 0..3
    const int ln  = tid & 63;
    const int lo  = ln & 15;
    const int g4  = ln >> 4;    // 0..3

    if (tid < EPB) {
        ssrc[tid] = esrc[e0 + tid];
        sdst[tid] = edst[e0 + tid];
    }

    // hoist phase-2 ks=0 B-frags (w2T, L2-resident) above phase-1
    const unsigned short* bbase = w2T + (size_t)(64 * w + lo) * HH + 8 * g4;
    bf16x8 bcur[4], bnxt[4];
    #pragma unroll
    for (int nt = 0; nt < 4; ++nt) bcur[nt] = *(const bf16x8*)(bbase + nt * 16 * HH);

    // ---- phase 1 (transposed): hT[j][t] = leaky(sum_k w1T[j][k] ea[t][k] + b1[j]) ----
    bf16x8 zero8;
    #pragma unroll
    for (int k = 0; k < 8; ++k) zero8[k] = 0;

    bf16x8 aW[4], bE[4];   // A = w1 rows (j), B = ea rows (t); K padded 8->32
    #pragma unroll
    for (int q = 0; q < 4; ++q) { aW[q] = zero8; bE[q] = zero8; }

    if (ln < 16) {  // g4==0 lanes carry k=0..7; others zero
        #pragma unroll
        for (int jj = 0; jj < 4; ++jj)
            aW[jj] = *(const bf16x8*)(w1T + ((4 * w + jj) * 16 + lo) * EAD);
        #pragma unroll
        for (int tb = 0; tb < 4; ++tb) {
            const float4* p = (const float4*)(ea + (size_t)(e0 + 16 * tb + lo) * EAD);
            float4 a0 = p[0], a1 = p[1];       // vectorized 2x16B row load
            bf16x8 v;
            v[0] = (short)f2bf(a0.x); v[1] = (short)f2bf(a0.y);
            v[2] = (short)f2bf(a0.z); v[3] = (short)f2bf(a0.w);
            v[4] = (short)f2bf(a1.x); v[5] = (short)f2bf(a1.y);
            v[6] = (short)f2bf(a1.z); v[7] = (short)f2bf(a1.w);
            bE[tb] = v;
        }
    }

    f32x4 hacc[4][4];   // [jj][tb]
    #pragma unroll
    for (int jj = 0; jj < 4; ++jj) {
        float4 bv = *(const float4*)(b1 + (4 * w + jj) * 16 + 4 * g4);  // b1[j0..j0+3]
        f32x4 bi; bi[0] = bv.x; bi[1] = bv.y; bi[2] = bv.z; bi[3] = bv.w;
        #pragma unroll
        for (int tb = 0; tb < 4; ++tb) hacc[jj][tb] = bi;
    }
    #pragma unroll
    for (int jj = 0; jj < 4; ++jj)
        #pragma unroll
        for (int tb = 0; tb < 4; ++tb)
            hacc[jj][tb] = __builtin_amdgcn_mfma_f32_16x16x32_bf16(aW[jj], bE[tb], hacc[jj][tb], 0, 0, 0);

    // leaky + pack 4 consecutive j (D rows) -> one b64 store, swizzled
    #pragma unroll
    for (int jj = 0; jj < 4; ++jj) {
        const int j0 = 64 * w + 16 * jj + 4 * g4;
        #pragma unroll
        for (int tb = 0; tb < 4; ++tb) {
            const int t = 16 * tb + lo;
            unsigned int u0 = (unsigned int)f2bf(leakyf(hacc[jj][tb][0]))
                            | ((unsigned int)f2bf(leakyf(hacc[jj][tb][1])) << 16);
            unsigned int u1 = (unsigned int)f2bf(leakyf(hacc[jj][tb][2]))
                            | ((unsigned int)f2bf(leakyf(hacc[jj][tb][3])) << 16);
            uint2 pk; pk.x = u0; pk.y = u1;
            *(uint2*)&h_us[HSWZ(t, t * HH + j0)] = pk;
        }
    }
    __syncthreads();   // barrier 1: h ready

    // ---- phase 2: W = h @ w2 + b2  (M=64 edges, N=256 cols, K=256) ----
    f32x4 acc[4][4];
    #pragma unroll
    for (int nt = 0; nt < 4; ++nt) {
        float bv = b2[64 * w + 16 * nt + lo];
        f32x4 bi; bi[0] = bv; bi[1] = bv; bi[2] = bv; bi[3] = bv;
        #pragma unroll
        for (int mt = 0; mt < 4; ++mt) acc[mt][nt] = bi;
    }
    #pragma unroll
    for (int ks = 0; ks < 8; ++ks) {
        if (ks < 7) {
            #pragma unroll
            for (int nt = 0; nt < 4; ++nt)
                bnxt[nt] = *(const bf16x8*)(bbase + nt * 16 * HH + 32 * (ks + 1));
        }
        bf16x8 af[4];   // lane: h[t=16mt+lo][j=32ks+8g4 .. +8]
        #pragma unroll
        for (int mt = 0; mt < 4; ++mt) {
            int t = 16 * mt + lo;
            af[mt] = *(const bf16x8*)(h_us + HSWZ(t, t * HH + 32 * ks + 8 * g4));
        }
        #pragma unroll
        for (int mt = 0; mt < 4; ++mt)
            #pragma unroll
            for (int nt = 0; nt < 4; ++nt)
                acc[mt][nt] = __builtin_amdgcn_mfma_f32_16x16x32_bf16(af[mt], bcur[nt], acc[mt][nt], 0, 0, 0);
        #pragma unroll
        for (int nt = 0; nt < 4; ++nt) bcur[nt] = bnxt[nt];
    }
    __syncthreads();   // barrier 2: all h reads done -> h_us reusable

    // ---- epilogue: per-wave partial msg into reused h_us region ----
    // lane's col c = 64w+16nt+lo -> i = 4w+nt, o = lo; D row -> t = 16mt+4g4+r
    float* msgp = (float*)h_us;   // [4][EPB][MPS] = 17408 B < 32 KB
    #pragma unroll
    for (int mt = 0; mt < 4; ++mt)
        #pragma unroll
        for (int r = 0; r < 4; ++r) {
            const int t = 16 * mt + 4 * g4 + r;
            float4 xv = *(const float4*)(x + (size_t)ssrc[t] * DIN + 4 * w);  // 16-lane broadcast
            float ps = xv.x * acc[mt][0][r] + xv.y * acc[mt][1][r]
                     + xv.z * acc[mt][2][r] + xv.w * acc[mt][3][r];
            msgp[(w * EPB + t) * MPS + lo] = ps;
        }
    __syncthreads();   // barrier 3: msg partials ready

    // ---- tail: sum 4 wave-partials, scatter with global fp32 atomics ----
    {
        const int t = tid >> 2, p = tid & 3;
        const int d = sdst[t];
        #pragma unroll
        for (int oo = 0; oo < 4; ++oo) {
            const int o = 4 * p + oo;
            float m = msgp[(0 * EPB + t) * MPS + o] + msgp[(1 * EPB + t) * MPS + o]
                    + msgp[(2 * EPB + t) * MPS + o] + msgp[(3 * EPB + t) * MPS + o];
            atomicAdd(&agg[(size_t)d * DOUT + o], m);
        }
        if (COUNT && p == 0) atomicAdd(&cnt[d], 1.0f);
    }
}

// out[n][o] = agg[n][o]/max(cnt,1) + x[n]@root[:,o] + bias[o]  (opt leaky)
__global__ void finalize_kernel(const float* __restrict__ agg,
                                const float* __restrict__ cnt,
                                const float* __restrict__ xin,
                                const float* __restrict__ root, // [16,16]
                                const float* __restrict__ bias, // [16]
                                float* __restrict__ out,
                                int do_leaky)
{
    int idx = blockIdx.x * blockDim.x + threadIdx.x;
    if (idx >= NN * DOUT) return;
    int n = idx >> 4, o = idx & 15;
    float c = cnt[n];
    c = c > 1.f ? c : 1.f;
    float v = agg[idx] / c;
    #pragma unroll
    for (int i = 0; i < DIN; ++i)
        v += xin[n * DIN + i] * root[i * DOUT + o];
    v += bias[o];
    out[idx] = do_leaky ? leakyf(v) : v;
}

extern "C" void kernel_launch(void* const* d_in, const int* in_sizes, int n_in,
                              void* d_out, int out_size, void* d_ws, size_t ws_size,
                              hipStream_t stream)
{
    const float* x      = (const float*)d_in[0];
    const int*   ei     = (const int*)  d_in[1];
    const float* ea     = (const float*)d_in[2];
    const float* w1_0   = (const float*)d_in[3];
    const float* b1_0   = (const float*)d_in[4];
    const float* w2_0   = (const float*)d_in[5];
    const float* b2_0   = (const float*)d_in[6];
    const float* root_0 = (const float*)d_in[7];
    const float* bias_0 = (const float*)d_in[8];
    const float* w1_1   = (const float*)d_in[9];
    const float* b1_1   = (const float*)d_in[10];
    const float* w2_1   = (const float*)d_in[11];
    const float* b2_1   = (const float*)d_in[12];
    const float* root_1 = (const float*)d_in[13];
    const float* bias_1 = (const float*)d_in[14];

    const int* esrc = ei;
    const int* edst = ei + NE;

    // ws: w2T0|w2T1 (bf16) | w1T0|w1T1 (bf16) | agg | cnt | x1 (f32)
    unsigned short* w2T0 = (unsigned short*)d_ws;
    unsigned short* w2T1 = w2T0 + HH * HH;
    unsigned short* w1T0 = w2T1 + HH * HH;
    unsigned short* w1T1 = w1T0 + HH * EAD;
    float* agg = (float*)(w1T1 + HH * EAD);
    float* cnt = agg + (size_t)NN * DOUT;
    float* x1  = cnt + NN;
    const size_t ws_need = (size_t)((char*)(x1 + (size_t)NN * DIN) - (char*)d_ws);
    if (ws_size < ws_need) return;  // fail clean (absmax), not a GPU fault

    hipMemsetAsync(agg, 0, ((size_t)NN * DOUT + NN) * sizeof(float), stream);
    prep_kernel<<<HH * HH / 256, 256, 0, stream>>>(w2_0, w2_1, w1_0, w1_1,
                                                   w2T0, w2T1, w1T0, w1T1);

    edge_kernel<1><<<NE / EPB, 256, 0, stream>>>(x, esrc, edst, ea,
                                                 w1T0, b1_0, w2T0, b2_0, agg, cnt);
    finalize_kernel<<<(NN * DOUT + 255) / 256, 256, 0, stream>>>(agg, cnt, x,
                                                 root_0, bias_0, x1, 1);
    hipMemsetAsync(agg, 0, (size_t)NN * DOUT * sizeof(float), stream);

    edge_kernel<0><<<NE / EPB, 256, 0, stream>>>(x1, esrc, edst, ea,
                                                 w1T1, b1_1, w2T1, b2_1, agg, cnt);
    finalize_kernel<<<(NN * DOUT + 255) / 256, 256, 0, stream>>>(agg, cnt, x1,
                                                 root_1, bias_1, (float*)d_out, 0);
}